// Round 1
// baseline (2326.448 us; speedup 1.0000x reference)
//
#include <hip/hip_runtime.h>
#include <hip/hip_bf16.h>
#include <math.h>

// DAGNN: h = relu(x@W1+b1)@W2+b2 ; 10x GCN-normalized propagation (CSR by dest,
// built on-device each launch); adaptive hop pooling fused into each hop epilogue.
// All fp32 this round (correctness-first). Edge dtype (int32 vs int64) detected
// at runtime via odd-word probe.

#define WAVE 64

// ---- edge dtype detection: stride 1 (int32) or 2 (int64 low words) ----
__global__ void detect_kernel(const unsigned* __restrict__ e, int* __restrict__ sflag) {
    __shared__ int any;
    if (threadIdx.x == 0) any = 0;
    __syncthreads();
    unsigned nz = 0;
    int t = threadIdx.x;
    for (int i = 0; i < 8; ++i) nz |= e[(size_t)(t * 8 + i) * 2 + 1];
    if (nz) atomicOr(&any, 1);
    __syncthreads();
    if (t == 0) *sflag = any ? 1 : 2;
}

__global__ void init_deg_kernel(int* __restrict__ deg, int n) {
    int i = blockIdx.x * blockDim.x + threadIdx.x;
    if (i < n) deg[i] = 1;  // self-loop contributes 1
}

__global__ void count_deg_kernel(const int* __restrict__ eidx, const int* __restrict__ sflag,
                                 int* __restrict__ deg, int E) {
    int e = blockIdx.x * blockDim.x + threadIdx.x;
    int s = *sflag;
    if (e < E) {
        int c = eidx[(size_t)s * (size_t)(E + e)];
        atomicAdd(&deg[c], 1);
    }
}

__global__ void dinv_kernel(const int* __restrict__ deg, float* __restrict__ dinv, int n) {
    int i = blockIdx.x * blockDim.x + threadIdx.x;
    if (i < n) dinv[i] = rsqrtf((float)deg[i]);
}

// ---- exclusive scan of deg -> offs (3 kernels, 1024 elems/block) ----
__global__ void scan1_kernel(const int* __restrict__ deg, int* __restrict__ out,
                             int* __restrict__ bsums, int n) {
    __shared__ int s[256];
    int t = threadIdx.x;
    int idx = blockIdx.x * 1024 + t * 4;
    int x0 = (idx + 0 < n) ? deg[idx + 0] : 0;
    int x1 = (idx + 1 < n) ? deg[idx + 1] : 0;
    int x2 = (idx + 2 < n) ? deg[idx + 2] : 0;
    int x3 = (idx + 3 < n) ? deg[idx + 3] : 0;
    int lsum = x0 + x1 + x2 + x3;
    s[t] = lsum;
    __syncthreads();
    for (int o = 1; o < 256; o <<= 1) {
        int v = (t >= o) ? s[t - o] : 0;
        __syncthreads();
        if (t >= o) s[t] += v;
        __syncthreads();
    }
    int excl = s[t] - lsum;
    if (idx + 0 < n) out[idx + 0] = excl;
    if (idx + 1 < n) out[idx + 1] = excl + x0;
    if (idx + 2 < n) out[idx + 2] = excl + x0 + x1;
    if (idx + 3 < n) out[idx + 3] = excl + x0 + x1 + x2;
    if (t == 255) bsums[blockIdx.x] = s[255];
}

__global__ void scan2_kernel(int* __restrict__ bsums, int nb) {
    __shared__ int s[256];
    int t = threadIdx.x;
    int v = (t < nb) ? bsums[t] : 0;
    s[t] = v;
    __syncthreads();
    for (int o = 1; o < 256; o <<= 1) {
        int x = (t >= o) ? s[t - o] : 0;
        __syncthreads();
        if (t >= o) s[t] += x;
        __syncthreads();
    }
    if (t < nb) bsums[t] = s[t] - v;  // exclusive block offsets
}

__global__ void scan3_kernel(int* __restrict__ offs, const int* __restrict__ bsums,
                             int* __restrict__ cursor, int n, int total) {
    int t = threadIdx.x;
    int idx = blockIdx.x * 1024 + t * 4;
    int add = bsums[blockIdx.x];
    #pragma unroll
    for (int i = 0; i < 4; ++i) {
        if (idx + i < n) {
            int v = offs[idx + i] + add;
            offs[idx + i] = v;
            cursor[idx + i] = v;
        }
    }
    if (blockIdx.x == 0 && t == 0) offs[n] = total;
}

__global__ void fill_csr_kernel(const int* __restrict__ eidx, const int* __restrict__ sflag,
                                const float* __restrict__ dinv, int* __restrict__ cursor,
                                int* __restrict__ csr_src, float* __restrict__ csr_w,
                                int E, int n) {
    int t = blockIdx.x * blockDim.x + threadIdx.x;
    int s = *sflag;
    int r, c;
    if (t < E) {
        r = eidx[(size_t)s * (size_t)t];
        c = eidx[(size_t)s * (size_t)(E + t)];
    } else if (t < E + n) {
        r = t - E;
        c = r;
    } else {
        return;
    }
    float w = dinv[r] * dinv[c];
    int pos = atomicAdd(&cursor[c], 1);
    csr_src[pos] = r;
    csr_w[pos] = w;
}

// ---- fp32 GEMM, K fixed = 256, 64x64 tile, 256 threads, 4x4 per thread ----
__global__ __launch_bounds__(256) void gemm_kernel(
        const float* __restrict__ A, int lda,
        const float* __restrict__ B, int ldb,
        const float* __restrict__ bias,
        float* __restrict__ C, int ldc,
        int M, int relu) {
    __shared__ float As[16][68];
    __shared__ float Bs[16][68];
    int tid = threadIdx.x;
    int tx = tid & 15, ty = tid >> 4;
    int bm = blockIdx.y * 64, bn = blockIdx.x * 64;
    float acc[4][4] = {};
    for (int k0 = 0; k0 < 256; k0 += 16) {
        int ka = tid & 15, ma = tid >> 4;
        #pragma unroll
        for (int p = 0; p < 4; ++p) {
            int m = ma + p * 16;
            int row = bm + m;
            As[ka][m] = (row < M) ? A[(size_t)row * lda + k0 + ka] : 0.f;
        }
        int nb_ = tid & 63, kb = tid >> 6;
        #pragma unroll
        for (int p = 0; p < 4; ++p) {
            int k = kb + p * 4;
            Bs[k][nb_] = B[(size_t)(k0 + k) * ldb + bn + nb_];
        }
        __syncthreads();
        #pragma unroll
        for (int kk = 0; kk < 16; ++kk) {
            float4 av = *(const float4*)&As[kk][ty * 4];
            float4 bv = *(const float4*)&Bs[kk][tx * 4];
            float a[4] = {av.x, av.y, av.z, av.w};
            float b[4] = {bv.x, bv.y, bv.z, bv.w};
            #pragma unroll
            for (int i = 0; i < 4; ++i)
                #pragma unroll
                for (int j = 0; j < 4; ++j)
                    acc[i][j] = fmaf(a[i], b[j], acc[i][j]);
        }
        __syncthreads();
    }
    #pragma unroll
    for (int i = 0; i < 4; ++i) {
        int row = bm + ty * 4 + i;
        if (row < M) {
            float4 o;
            o.x = acc[i][0] + bias[bn + tx * 4 + 0];
            o.y = acc[i][1] + bias[bn + tx * 4 + 1];
            o.z = acc[i][2] + bias[bn + tx * 4 + 2];
            o.w = acc[i][3] + bias[bn + tx * 4 + 3];
            if (relu) {
                o.x = fmaxf(o.x, 0.f); o.y = fmaxf(o.y, 0.f);
                o.z = fmaxf(o.z, 0.f); o.w = fmaxf(o.w, 0.f);
            }
            *(float4*)&C[(size_t)row * ldc + bn + tx * 4] = o;
        }
    }
}

// ---- hop 0: out = sigmoid(h.pw + pb) * h ----
__global__ void hop0_kernel(const float* __restrict__ h, const float* __restrict__ pw,
                            const float* __restrict__ pb, float* __restrict__ out, int n) {
    int wid = (blockIdx.x * blockDim.x + threadIdx.x) >> 6;
    int lane = threadIdx.x & 63;
    if (wid >= n) return;
    float v = h[(size_t)wid * 64 + lane];
    float d = v * pw[lane];
    #pragma unroll
    for (int o = 32; o > 0; o >>= 1) d += __shfl_xor(d, o, 64);
    float sg = 1.f / (1.f + __expf(-(d + pb[0])));
    out[(size_t)wid * 64 + lane] = sg * v;
}

// ---- one propagation hop + fused pooling epilogue; wave per dest node ----
__global__ void spmm_kernel(const int* __restrict__ offs, const int* __restrict__ src,
                            const float* __restrict__ w, const float* __restrict__ hin,
                            float* __restrict__ hout, float* __restrict__ out,
                            const float* __restrict__ pw, const float* __restrict__ pb,
                            int n) {
    int wid = (blockIdx.x * blockDim.x + threadIdx.x) >> 6;
    int lane = threadIdx.x & 63;
    if (wid >= n) return;
    int c = __builtin_amdgcn_readfirstlane(wid);
    int e = offs[c], eend = offs[c + 1];
    float acc = 0.f;
    for (; e + 3 < eend; e += 4) {
        int s0 = src[e], s1 = src[e + 1], s2 = src[e + 2], s3 = src[e + 3];
        float w0 = w[e], w1 = w[e + 1], w2 = w[e + 2], w3 = w[e + 3];
        float v0 = hin[(size_t)s0 * 64 + lane];
        float v1 = hin[(size_t)s1 * 64 + lane];
        float v2 = hin[(size_t)s2 * 64 + lane];
        float v3 = hin[(size_t)s3 * 64 + lane];
        acc = fmaf(w0, v0, acc);
        acc = fmaf(w1, v1, acc);
        acc = fmaf(w2, v2, acc);
        acc = fmaf(w3, v3, acc);
    }
    for (; e < eend; ++e) acc = fmaf(w[e], hin[(size_t)src[e] * 64 + lane], acc);
    hout[(size_t)wid * 64 + lane] = acc;
    float d = acc * pw[lane];
    #pragma unroll
    for (int o = 32; o > 0; o >>= 1) d += __shfl_xor(d, o, 64);
    float sg = 1.f / (1.f + __expf(-(d + pb[0])));
    size_t oi = (size_t)wid * 64 + lane;
    out[oi] += sg * acc;
}

extern "C" void kernel_launch(void* const* d_in, const int* in_sizes, int n_in,
                              void* d_out, int out_size, void* d_ws, size_t ws_size,
                              hipStream_t stream) {
    const float* x  = (const float*)d_in[0];
    const int* eidx = (const int*)d_in[1];
    const float* W1 = (const float*)d_in[2];
    const float* b1 = (const float*)d_in[3];
    const float* W2 = (const float*)d_in[4];
    const float* b2 = (const float*)d_in[5];
    const float* pw = (const float*)d_in[6];
    const float* pb = (const float*)d_in[7];
    float* out = (float*)d_out;

    const int N = in_sizes[0] / 256;
    const int E = in_sizes[1] / 2;
    const int NNZ = E + N;

    size_t woff = 0;
    auto alloc = [&](size_t bytes) -> void* {
        void* p = (char*)d_ws + woff;
        woff += (bytes + 255) & ~(size_t)255;
        return p;
    };
    int*   sflag   = (int*)alloc(4);
    int*   deg     = (int*)alloc((size_t)N * 4);
    float* dinv    = (float*)alloc((size_t)N * 4);
    int*   offs    = (int*)alloc(((size_t)N + 1) * 4);
    int*   cursor  = (int*)alloc((size_t)N * 4);
    int*   bsums   = (int*)alloc(256 * 4);
    int*   csr_src = (int*)alloc((size_t)NNZ * 4);
    float* csr_w   = (float*)alloc((size_t)NNZ * 4);
    const int CH = 12800;
    float* h1 = (float*)alloc((size_t)CH * 256 * 4);
    float* hA = (float*)alloc((size_t)N * 64 * 4);
    float* hB = (float*)alloc((size_t)N * 64 * 4);

    detect_kernel<<<1, 256, 0, stream>>>((const unsigned*)eidx, sflag);
    init_deg_kernel<<<(N + 255) / 256, 256, 0, stream>>>(deg, N);
    count_deg_kernel<<<(E + 255) / 256, 256, 0, stream>>>(eidx, sflag, deg, E);
    dinv_kernel<<<(N + 255) / 256, 256, 0, stream>>>(deg, dinv, N);
    int nb = (N + 1023) / 1024;
    scan1_kernel<<<nb, 256, 0, stream>>>(deg, offs, bsums, N);
    scan2_kernel<<<1, 256, 0, stream>>>(bsums, nb);
    scan3_kernel<<<nb, 256, 0, stream>>>(offs, bsums, cursor, N, NNZ);
    fill_csr_kernel<<<(NNZ + 255) / 256, 256, 0, stream>>>(eidx, sflag, dinv, cursor,
                                                           csr_src, csr_w, E, N);

    for (int ms = 0; ms < N; ms += CH) {
        int mc = (N - ms < CH) ? (N - ms) : CH;
        dim3 g1(4, (mc + 63) / 64);
        gemm_kernel<<<g1, 256, 0, stream>>>(x + (size_t)ms * 256, 256, W1, 256, b1,
                                            h1, 256, mc, 1);
        dim3 g2(1, (mc + 63) / 64);
        gemm_kernel<<<g2, 256, 0, stream>>>(h1, 256, W2, 64, b2,
                                            hA + (size_t)ms * 64, 64, mc, 0);
    }

    int nwb = (N + 3) / 4;  // 4 waves (=4 nodes) per 256-thread block
    hop0_kernel<<<nwb, 256, 0, stream>>>(hA, pw, pb, out, N);
    float* hin = hA;
    float* hout = hB;
    for (int k = 0; k < 10; ++k) {
        spmm_kernel<<<nwb, 256, 0, stream>>>(offs, csr_src, csr_w, hin, hout, out, pw, pb, N);
        float* t = hin; hin = hout; hout = t;
    }
}

// Round 2
// 2038.903 us; speedup vs baseline: 1.1410x; 1.1410x over previous
//
#include <hip/hip_runtime.h>
#include <hip/hip_bf16.h>
#include <math.h>

// DAGNN r2: state refactor g = dinv*h  =>  h_next[c] = dinv[c]*(g[c] + sum_{r->c} g[r]).
// CSR holds only src indices (no weights, no self-loop entries). Pooling fused
// into each hop epilogue. fp32 throughout.

#define WAVE 64

// ---- edge dtype detection: stride 1 (int32) or 2 (int64 low words) ----
__global__ void detect_kernel(const unsigned* __restrict__ e, int* __restrict__ sflag) {
    __shared__ int any;
    if (threadIdx.x == 0) any = 0;
    __syncthreads();
    unsigned nz = 0;
    int t = threadIdx.x;
    for (int i = 0; i < 8; ++i) nz |= e[(size_t)(t * 8 + i) * 2 + 1];
    if (nz) atomicOr(&any, 1);
    __syncthreads();
    if (t == 0) *sflag = any ? 1 : 2;
}

__global__ void init_cnt_kernel(int* __restrict__ cnt, int n) {
    int i = blockIdx.x * blockDim.x + threadIdx.x;
    if (i < n) cnt[i] = 0;
}

__global__ void count_deg_kernel(const int* __restrict__ eidx, const int* __restrict__ sflag,
                                 int* __restrict__ cnt, int E) {
    int e = blockIdx.x * blockDim.x + threadIdx.x;
    int s = *sflag;
    if (e < E) {
        int c = eidx[(size_t)s * (size_t)(E + e)];
        atomicAdd(&cnt[c], 1);
    }
}

__global__ void dinv_kernel(const int* __restrict__ cnt, float* __restrict__ dinv, int n) {
    int i = blockIdx.x * blockDim.x + threadIdx.x;
    if (i < n) dinv[i] = rsqrtf((float)(cnt[i] + 1));  // self-loop adds 1 to degree
}

// ---- exclusive scan of cnt -> offs ----
__global__ void scan1_kernel(const int* __restrict__ cnt, int* __restrict__ out,
                             int* __restrict__ bsums, int n) {
    __shared__ int s[256];
    int t = threadIdx.x;
    int idx = blockIdx.x * 1024 + t * 4;
    int x0 = (idx + 0 < n) ? cnt[idx + 0] : 0;
    int x1 = (idx + 1 < n) ? cnt[idx + 1] : 0;
    int x2 = (idx + 2 < n) ? cnt[idx + 2] : 0;
    int x3 = (idx + 3 < n) ? cnt[idx + 3] : 0;
    int lsum = x0 + x1 + x2 + x3;
    s[t] = lsum;
    __syncthreads();
    for (int o = 1; o < 256; o <<= 1) {
        int v = (t >= o) ? s[t - o] : 0;
        __syncthreads();
        if (t >= o) s[t] += v;
        __syncthreads();
    }
    int excl = s[t] - lsum;
    if (idx + 0 < n) out[idx + 0] = excl;
    if (idx + 1 < n) out[idx + 1] = excl + x0;
    if (idx + 2 < n) out[idx + 2] = excl + x0 + x1;
    if (idx + 3 < n) out[idx + 3] = excl + x0 + x1 + x2;
    if (t == 255) bsums[blockIdx.x] = s[255];
}

__global__ void scan2_kernel(int* __restrict__ bsums, int nb) {
    __shared__ int s[256];
    int t = threadIdx.x;
    int v = (t < nb) ? bsums[t] : 0;
    s[t] = v;
    __syncthreads();
    for (int o = 1; o < 256; o <<= 1) {
        int x = (t >= o) ? s[t - o] : 0;
        __syncthreads();
        if (t >= o) s[t] += x;
        __syncthreads();
    }
    if (t < nb) bsums[t] = s[t] - v;
}

__global__ void scan3_kernel(int* __restrict__ offs, const int* __restrict__ bsums,
                             int* __restrict__ cursor, int n, int total) {
    int t = threadIdx.x;
    int idx = blockIdx.x * 1024 + t * 4;
    int add = bsums[blockIdx.x];
    #pragma unroll
    for (int i = 0; i < 4; ++i) {
        if (idx + i < n) {
            int v = offs[idx + i] + add;
            offs[idx + i] = v;
            cursor[idx + i] = v;
        }
    }
    if (blockIdx.x == 0 && t == 0) offs[n] = total;
}

__global__ void fill_csr_kernel(const int* __restrict__ eidx, const int* __restrict__ sflag,
                                int* __restrict__ cursor, int* __restrict__ csr_src, int E) {
    int t = blockIdx.x * blockDim.x + threadIdx.x;
    if (t >= E) return;
    int s = *sflag;
    int r = eidx[(size_t)s * (size_t)t];
    int c = eidx[(size_t)s * (size_t)(E + t)];
    int pos = atomicAdd(&cursor[c], 1);
    csr_src[pos] = r;
}

// ---- fp32 GEMM, K fixed = 256, 64x64 tile, 256 threads, 4x4 per thread ----
__global__ __launch_bounds__(256) void gemm_kernel(
        const float* __restrict__ A, int lda,
        const float* __restrict__ B, int ldb,
        const float* __restrict__ bias,
        float* __restrict__ C, int ldc,
        int M, int relu) {
    __shared__ float As[16][68];
    __shared__ float Bs[16][68];
    int tid = threadIdx.x;
    int tx = tid & 15, ty = tid >> 4;
    int bm = blockIdx.y * 64, bn = blockIdx.x * 64;
    float acc[4][4] = {};
    for (int k0 = 0; k0 < 256; k0 += 16) {
        int ka = tid & 15, ma = tid >> 4;
        #pragma unroll
        for (int p = 0; p < 4; ++p) {
            int m = ma + p * 16;
            int row = bm + m;
            As[ka][m] = (row < M) ? A[(size_t)row * lda + k0 + ka] : 0.f;
        }
        int nb_ = tid & 63, kb = tid >> 6;
        #pragma unroll
        for (int p = 0; p < 4; ++p) {
            int k = kb + p * 4;
            Bs[k][nb_] = B[(size_t)(k0 + k) * ldb + bn + nb_];
        }
        __syncthreads();
        #pragma unroll
        for (int kk = 0; kk < 16; ++kk) {
            float4 av = *(const float4*)&As[kk][ty * 4];
            float4 bv = *(const float4*)&Bs[kk][tx * 4];
            float a[4] = {av.x, av.y, av.z, av.w};
            float b[4] = {bv.x, bv.y, bv.z, bv.w};
            #pragma unroll
            for (int i = 0; i < 4; ++i)
                #pragma unroll
                for (int j = 0; j < 4; ++j)
                    acc[i][j] = fmaf(a[i], b[j], acc[i][j]);
        }
        __syncthreads();
    }
    #pragma unroll
    for (int i = 0; i < 4; ++i) {
        int row = bm + ty * 4 + i;
        if (row < M) {
            float4 o;
            o.x = acc[i][0] + bias[bn + tx * 4 + 0];
            o.y = acc[i][1] + bias[bn + tx * 4 + 1];
            o.z = acc[i][2] + bias[bn + tx * 4 + 2];
            o.w = acc[i][3] + bias[bn + tx * 4 + 3];
            if (relu) {
                o.x = fmaxf(o.x, 0.f); o.y = fmaxf(o.y, 0.f);
                o.z = fmaxf(o.z, 0.f); o.w = fmaxf(o.w, 0.f);
            }
            *(float4*)&C[(size_t)row * ldc + bn + tx * 4] = o;
        }
    }
}

// ---- hop 0: out = sigmoid(h.pw + pb)*h ; g0 = dinv*h ----
__global__ void hop0_kernel(const float* __restrict__ h, const float* __restrict__ dinv,
                            const float* __restrict__ pw, const float* __restrict__ pb,
                            float* __restrict__ out, float* __restrict__ g, int n) {
    int wid = (blockIdx.x * blockDim.x + threadIdx.x) >> 6;
    int lane = threadIdx.x & 63;
    if (wid >= n) return;
    float v = h[(size_t)wid * 64 + lane];
    float d = v * pw[lane];
    #pragma unroll
    for (int o = 32; o > 0; o >>= 1) d += __shfl_xor(d, o, 64);
    float sg = 1.f / (1.f + __expf(-(d + pb[0])));
    out[(size_t)wid * 64 + lane] = sg * v;
    g[(size_t)wid * 64 + lane] = dinv[wid] * v;
}

// ---- one hop: acc = sum g[src]; h = dinv[c]*(acc + g[c]); g_out = dinv[c]*h;
//      out += sigmoid(h.pw+pb)*h.  Wave per dest node. ----
__global__ void spmm_kernel(const int* __restrict__ offs, const int* __restrict__ src,
                            const float* __restrict__ dinv,
                            const float* __restrict__ gin, float* __restrict__ gout,
                            float* __restrict__ out,
                            const float* __restrict__ pw, const float* __restrict__ pb,
                            int n) {
    int wid = (blockIdx.x * blockDim.x + threadIdx.x) >> 6;
    int lane = threadIdx.x & 63;
    if (wid >= n) return;
    int c = __builtin_amdgcn_readfirstlane(wid);
    int e = __builtin_amdgcn_readfirstlane(offs[c]);
    int eend = __builtin_amdgcn_readfirstlane(offs[c + 1]);
    float acc = 0.f;
    // align e to 4 for vector index loads
    while (e < eend && (e & 3)) {
        acc += gin[(size_t)src[e] * 64 + lane];
        ++e;
    }
    for (; e + 7 < eend; e += 8) {
        int4 sa = *(const int4*)(src + e);
        int4 sb = *(const int4*)(src + e + 4);
        float v0 = gin[(size_t)sa.x * 64 + lane];
        float v1 = gin[(size_t)sa.y * 64 + lane];
        float v2 = gin[(size_t)sa.z * 64 + lane];
        float v3 = gin[(size_t)sa.w * 64 + lane];
        float v4 = gin[(size_t)sb.x * 64 + lane];
        float v5 = gin[(size_t)sb.y * 64 + lane];
        float v6 = gin[(size_t)sb.z * 64 + lane];
        float v7 = gin[(size_t)sb.w * 64 + lane];
        acc += ((v0 + v1) + (v2 + v3)) + ((v4 + v5) + (v6 + v7));
    }
    for (; e + 3 < eend; e += 4) {
        int4 sa = *(const int4*)(src + e);
        float v0 = gin[(size_t)sa.x * 64 + lane];
        float v1 = gin[(size_t)sa.y * 64 + lane];
        float v2 = gin[(size_t)sa.z * 64 + lane];
        float v3 = gin[(size_t)sa.w * 64 + lane];
        acc += (v0 + v1) + (v2 + v3);
    }
    for (; e < eend; ++e) acc += gin[(size_t)src[e] * 64 + lane];

    float dc = dinv[c];
    float h = dc * (acc + gin[(size_t)c * 64 + lane]);
    gout[(size_t)c * 64 + lane] = dc * h;
    float d = h * pw[lane];
    #pragma unroll
    for (int o = 32; o > 0; o >>= 1) d += __shfl_xor(d, o, 64);
    float sg = 1.f / (1.f + __expf(-(d + pb[0])));
    out[(size_t)c * 64 + lane] += sg * h;
}

extern "C" void kernel_launch(void* const* d_in, const int* in_sizes, int n_in,
                              void* d_out, int out_size, void* d_ws, size_t ws_size,
                              hipStream_t stream) {
    const float* x  = (const float*)d_in[0];
    const int* eidx = (const int*)d_in[1];
    const float* W1 = (const float*)d_in[2];
    const float* b1 = (const float*)d_in[3];
    const float* W2 = (const float*)d_in[4];
    const float* b2 = (const float*)d_in[5];
    const float* pw = (const float*)d_in[6];
    const float* pb = (const float*)d_in[7];
    float* out = (float*)d_out;

    const int N = in_sizes[0] / 256;
    const int E = in_sizes[1] / 2;

    size_t woff = 0;
    auto alloc = [&](size_t bytes) -> void* {
        void* p = (char*)d_ws + woff;
        woff += (bytes + 255) & ~(size_t)255;
        return p;
    };
    int*   sflag   = (int*)alloc(4);
    int*   cnt     = (int*)alloc((size_t)N * 4);
    float* dinv    = (float*)alloc((size_t)N * 4);
    int*   offs    = (int*)alloc(((size_t)N + 1) * 4);
    int*   cursor  = (int*)alloc((size_t)N * 4);
    int*   bsums   = (int*)alloc(256 * 4);
    int*   csr_src = (int*)alloc((size_t)E * 4);
    const int CH = 25600;
    float* h1 = (float*)alloc((size_t)CH * 256 * 4);
    float* hA = (float*)alloc((size_t)N * 64 * 4);
    float* hB = (float*)alloc((size_t)N * 64 * 4);

    detect_kernel<<<1, 256, 0, stream>>>((const unsigned*)eidx, sflag);
    init_cnt_kernel<<<(N + 255) / 256, 256, 0, stream>>>(cnt, N);
    count_deg_kernel<<<(E + 255) / 256, 256, 0, stream>>>(eidx, sflag, cnt, E);
    dinv_kernel<<<(N + 255) / 256, 256, 0, stream>>>(cnt, dinv, N);
    int nb = (N + 1023) / 1024;
    scan1_kernel<<<nb, 256, 0, stream>>>(cnt, offs, bsums, N);
    scan2_kernel<<<1, 256, 0, stream>>>(bsums, nb);
    scan3_kernel<<<nb, 256, 0, stream>>>(offs, bsums, cursor, N, E);
    fill_csr_kernel<<<(E + 255) / 256, 256, 0, stream>>>(eidx, sflag, cursor, csr_src, E);

    for (int ms = 0; ms < N; ms += CH) {
        int mc = (N - ms < CH) ? (N - ms) : CH;
        dim3 g1(4, (mc + 63) / 64);
        gemm_kernel<<<g1, 256, 0, stream>>>(x + (size_t)ms * 256, 256, W1, 256, b1,
                                            h1, 256, mc, 1);
        dim3 g2(1, (mc + 63) / 64);
        gemm_kernel<<<g2, 256, 0, stream>>>(h1, 256, W2, 64, b2,
                                            hA + (size_t)ms * 64, 64, mc, 0);
    }

    int nwb = (N + 3) / 4;  // 4 waves (=4 dest nodes) per 256-thread block
    hop0_kernel<<<nwb, 256, 0, stream>>>(hA, dinv, pw, pb, out, hB, N);
    float* gin = hB;
    float* gout = hA;
    for (int k = 0; k < 10; ++k) {
        spmm_kernel<<<nwb, 256, 0, stream>>>(offs, csr_src, dinv, gin, gout, out, pw, pb, N);
        float* t = gin; gin = gout; gout = t;
    }
}

// Round 3
// 1635.998 us; speedup vs baseline: 1.4220x; 1.2463x over previous
//
#include <hip/hip_runtime.h>
#include <hip/hip_bf16.h>
#include <math.h>

// DAGNN r3: propagation state g = dinv*h stored as bf16 (gather traffic halved);
// all arithmetic fp32. CSR (src-only) by dest; pooling fused per hop.

#define WAVE 64

// ---- edge dtype detection: stride 1 (int32) or 2 (int64 low words) ----
__global__ void detect_kernel(const unsigned* __restrict__ e, int* __restrict__ sflag) {
    __shared__ int any;
    if (threadIdx.x == 0) any = 0;
    __syncthreads();
    unsigned nz = 0;
    int t = threadIdx.x;
    for (int i = 0; i < 8; ++i) nz |= e[(size_t)(t * 8 + i) * 2 + 1];
    if (nz) atomicOr(&any, 1);
    __syncthreads();
    if (t == 0) *sflag = any ? 1 : 2;
}

__global__ void init_cnt_kernel(int* __restrict__ cnt, int n) {
    int i = blockIdx.x * blockDim.x + threadIdx.x;
    if (i < n) cnt[i] = 0;
}

__global__ void count_deg_kernel(const int* __restrict__ eidx, const int* __restrict__ sflag,
                                 int* __restrict__ cnt, int E) {
    int e = blockIdx.x * blockDim.x + threadIdx.x;
    int s = *sflag;
    if (e < E) {
        int c = eidx[(size_t)s * (size_t)(E + e)];
        atomicAdd(&cnt[c], 1);
    }
}

__global__ void dinv_kernel(const int* __restrict__ cnt, float* __restrict__ dinv, int n) {
    int i = blockIdx.x * blockDim.x + threadIdx.x;
    if (i < n) dinv[i] = rsqrtf((float)(cnt[i] + 1));  // self-loop adds 1
}

// ---- exclusive scan of cnt -> offs ----
__global__ void scan1_kernel(const int* __restrict__ cnt, int* __restrict__ out,
                             int* __restrict__ bsums, int n) {
    __shared__ int s[256];
    int t = threadIdx.x;
    int idx = blockIdx.x * 1024 + t * 4;
    int x0 = (idx + 0 < n) ? cnt[idx + 0] : 0;
    int x1 = (idx + 1 < n) ? cnt[idx + 1] : 0;
    int x2 = (idx + 2 < n) ? cnt[idx + 2] : 0;
    int x3 = (idx + 3 < n) ? cnt[idx + 3] : 0;
    int lsum = x0 + x1 + x2 + x3;
    s[t] = lsum;
    __syncthreads();
    for (int o = 1; o < 256; o <<= 1) {
        int v = (t >= o) ? s[t - o] : 0;
        __syncthreads();
        if (t >= o) s[t] += v;
        __syncthreads();
    }
    int excl = s[t] - lsum;
    if (idx + 0 < n) out[idx + 0] = excl;
    if (idx + 1 < n) out[idx + 1] = excl + x0;
    if (idx + 2 < n) out[idx + 2] = excl + x0 + x1;
    if (idx + 3 < n) out[idx + 3] = excl + x0 + x1 + x2;
    if (t == 255) bsums[blockIdx.x] = s[255];
}

__global__ void scan2_kernel(int* __restrict__ bsums, int nb) {
    __shared__ int s[256];
    int t = threadIdx.x;
    int v = (t < nb) ? bsums[t] : 0;
    s[t] = v;
    __syncthreads();
    for (int o = 1; o < 256; o <<= 1) {
        int x = (t >= o) ? s[t - o] : 0;
        __syncthreads();
        if (t >= o) s[t] += x;
        __syncthreads();
    }
    if (t < nb) bsums[t] = s[t] - v;
}

__global__ void scan3_kernel(int* __restrict__ offs, const int* __restrict__ bsums,
                             int* __restrict__ cursor, int n, int total) {
    int t = threadIdx.x;
    int idx = blockIdx.x * 1024 + t * 4;
    int add = bsums[blockIdx.x];
    #pragma unroll
    for (int i = 0; i < 4; ++i) {
        if (idx + i < n) {
            int v = offs[idx + i] + add;
            offs[idx + i] = v;
            cursor[idx + i] = v;
        }
    }
    if (blockIdx.x == 0 && t == 0) offs[n] = total;
}

__global__ void fill_csr_kernel(const int* __restrict__ eidx, const int* __restrict__ sflag,
                                int* __restrict__ cursor, int* __restrict__ csr_src, int E) {
    int t = blockIdx.x * blockDim.x + threadIdx.x;
    if (t >= E) return;
    int s = *sflag;
    int r = eidx[(size_t)s * (size_t)t];
    int c = eidx[(size_t)s * (size_t)(E + t)];
    int pos = atomicAdd(&cursor[c], 1);
    csr_src[pos] = r;
}

// ---- fp32 GEMM, K fixed = 256, 64x64 tile, 256 threads, 4x4 per thread ----
__global__ __launch_bounds__(256) void gemm_kernel(
        const float* __restrict__ A, int lda,
        const float* __restrict__ B, int ldb,
        const float* __restrict__ bias,
        float* __restrict__ C, int ldc,
        int M, int relu) {
    __shared__ float As[16][68];
    __shared__ float Bs[16][68];
    int tid = threadIdx.x;
    int tx = tid & 15, ty = tid >> 4;
    int bm = blockIdx.y * 64, bn = blockIdx.x * 64;
    float acc[4][4] = {};
    for (int k0 = 0; k0 < 256; k0 += 16) {
        int ka = tid & 15, ma = tid >> 4;
        #pragma unroll
        for (int p = 0; p < 4; ++p) {
            int m = ma + p * 16;
            int row = bm + m;
            As[ka][m] = (row < M) ? A[(size_t)row * lda + k0 + ka] : 0.f;
        }
        int nb_ = tid & 63, kb = tid >> 6;
        #pragma unroll
        for (int p = 0; p < 4; ++p) {
            int k = kb + p * 4;
            Bs[k][nb_] = B[(size_t)(k0 + k) * ldb + bn + nb_];
        }
        __syncthreads();
        #pragma unroll
        for (int kk = 0; kk < 16; ++kk) {
            float4 av = *(const float4*)&As[kk][ty * 4];
            float4 bv = *(const float4*)&Bs[kk][tx * 4];
            float a[4] = {av.x, av.y, av.z, av.w};
            float b[4] = {bv.x, bv.y, bv.z, bv.w};
            #pragma unroll
            for (int i = 0; i < 4; ++i)
                #pragma unroll
                for (int j = 0; j < 4; ++j)
                    acc[i][j] = fmaf(a[i], b[j], acc[i][j]);
        }
        __syncthreads();
    }
    #pragma unroll
    for (int i = 0; i < 4; ++i) {
        int row = bm + ty * 4 + i;
        if (row < M) {
            float4 o;
            o.x = acc[i][0] + bias[bn + tx * 4 + 0];
            o.y = acc[i][1] + bias[bn + tx * 4 + 1];
            o.z = acc[i][2] + bias[bn + tx * 4 + 2];
            o.w = acc[i][3] + bias[bn + tx * 4 + 3];
            if (relu) {
                o.x = fmaxf(o.x, 0.f); o.y = fmaxf(o.y, 0.f);
                o.z = fmaxf(o.z, 0.f); o.w = fmaxf(o.w, 0.f);
            }
            *(float4*)&C[(size_t)row * ldc + bn + tx * 4] = o;
        }
    }
}

// ---- hop 0: out = sigmoid(h.pw + pb)*h ; g0 = bf16(dinv*h) ----
__global__ void hop0_kernel(const float* __restrict__ h, const float* __restrict__ dinv,
                            const float* __restrict__ pw, const float* __restrict__ pb,
                            float* __restrict__ out, __hip_bfloat16* __restrict__ g, int n) {
    int wid = (blockIdx.x * blockDim.x + threadIdx.x) >> 6;
    int lane = threadIdx.x & 63;
    if (wid >= n) return;
    float v = h[(size_t)wid * 64 + lane];
    float d = v * pw[lane];
    #pragma unroll
    for (int o = 32; o > 0; o >>= 1) d += __shfl_xor(d, o, 64);
    float sg = 1.f / (1.f + __expf(-(d + pb[0])));
    out[(size_t)wid * 64 + lane] = sg * v;
    g[(size_t)wid * 64 + lane] = __float2bfloat16(dinv[wid] * v);
}

// ---- one hop: acc = sum g[src]; h = dinv[c]*(acc + g[c]); g_out = bf16(dinv[c]*h);
//      out += sigmoid(h.pw+pb)*h.  Wave per dest node, fp32 accumulate. ----
__global__ void spmm_kernel(const int* __restrict__ offs, const int* __restrict__ src,
                            const float* __restrict__ dinv,
                            const __hip_bfloat16* __restrict__ gin,
                            __hip_bfloat16* __restrict__ gout,
                            float* __restrict__ out,
                            const float* __restrict__ pw, const float* __restrict__ pb,
                            int n) {
    int wid = (blockIdx.x * blockDim.x + threadIdx.x) >> 6;
    int lane = threadIdx.x & 63;
    if (wid >= n) return;
    int c = __builtin_amdgcn_readfirstlane(wid);
    int e = __builtin_amdgcn_readfirstlane(offs[c]);
    int eend = __builtin_amdgcn_readfirstlane(offs[c + 1]);
    float acc = 0.f;
    while (e < eend && (e & 3)) {
        acc += __bfloat162float(gin[(size_t)src[e] * 64 + lane]);
        ++e;
    }
    for (; e + 7 < eend; e += 8) {
        int4 sa = *(const int4*)(src + e);
        int4 sb = *(const int4*)(src + e + 4);
        float v0 = __bfloat162float(gin[(size_t)sa.x * 64 + lane]);
        float v1 = __bfloat162float(gin[(size_t)sa.y * 64 + lane]);
        float v2 = __bfloat162float(gin[(size_t)sa.z * 64 + lane]);
        float v3 = __bfloat162float(gin[(size_t)sa.w * 64 + lane]);
        float v4 = __bfloat162float(gin[(size_t)sb.x * 64 + lane]);
        float v5 = __bfloat162float(gin[(size_t)sb.y * 64 + lane]);
        float v6 = __bfloat162float(gin[(size_t)sb.z * 64 + lane]);
        float v7 = __bfloat162float(gin[(size_t)sb.w * 64 + lane]);
        acc += ((v0 + v1) + (v2 + v3)) + ((v4 + v5) + (v6 + v7));
    }
    for (; e + 3 < eend; e += 4) {
        int4 sa = *(const int4*)(src + e);
        float v0 = __bfloat162float(gin[(size_t)sa.x * 64 + lane]);
        float v1 = __bfloat162float(gin[(size_t)sa.y * 64 + lane]);
        float v2 = __bfloat162float(gin[(size_t)sa.z * 64 + lane]);
        float v3 = __bfloat162float(gin[(size_t)sa.w * 64 + lane]);
        acc += (v0 + v1) + (v2 + v3);
    }
    for (; e < eend; ++e) acc += __bfloat162float(gin[(size_t)src[e] * 64 + lane]);

    float dc = dinv[c];
    float h = dc * (acc + __bfloat162float(gin[(size_t)c * 64 + lane]));
    gout[(size_t)c * 64 + lane] = __float2bfloat16(dc * h);
    float d = h * pw[lane];
    #pragma unroll
    for (int o = 32; o > 0; o >>= 1) d += __shfl_xor(d, o, 64);
    float sg = 1.f / (1.f + __expf(-(d + pb[0])));
    out[(size_t)c * 64 + lane] += sg * h;
}

extern "C" void kernel_launch(void* const* d_in, const int* in_sizes, int n_in,
                              void* d_out, int out_size, void* d_ws, size_t ws_size,
                              hipStream_t stream) {
    const float* x  = (const float*)d_in[0];
    const int* eidx = (const int*)d_in[1];
    const float* W1 = (const float*)d_in[2];
    const float* b1 = (const float*)d_in[3];
    const float* W2 = (const float*)d_in[4];
    const float* b2 = (const float*)d_in[5];
    const float* pw = (const float*)d_in[6];
    const float* pb = (const float*)d_in[7];
    float* out = (float*)d_out;

    const int N = in_sizes[0] / 256;
    const int E = in_sizes[1] / 2;

    size_t woff = 0;
    auto alloc = [&](size_t bytes) -> void* {
        void* p = (char*)d_ws + woff;
        woff += (bytes + 255) & ~(size_t)255;
        return p;
    };
    int*   sflag   = (int*)alloc(4);
    int*   cnt     = (int*)alloc((size_t)N * 4);
    float* dinv    = (float*)alloc((size_t)N * 4);
    int*   offs    = (int*)alloc(((size_t)N + 1) * 4);
    int*   cursor  = (int*)alloc((size_t)N * 4);
    int*   bsums   = (int*)alloc(256 * 4);
    int*   csr_src = (int*)alloc((size_t)E * 4);
    const int CH = 25600;
    float* h1 = (float*)alloc((size_t)CH * 256 * 4);
    float* hA = (float*)alloc((size_t)N * 64 * 4);
    __hip_bfloat16* gA = (__hip_bfloat16*)alloc((size_t)N * 64 * 2);
    __hip_bfloat16* gB = (__hip_bfloat16*)alloc((size_t)N * 64 * 2);

    detect_kernel<<<1, 256, 0, stream>>>((const unsigned*)eidx, sflag);
    init_cnt_kernel<<<(N + 255) / 256, 256, 0, stream>>>(cnt, N);
    count_deg_kernel<<<(E + 255) / 256, 256, 0, stream>>>(eidx, sflag, cnt, E);
    dinv_kernel<<<(N + 255) / 256, 256, 0, stream>>>(cnt, dinv, N);
    int nb = (N + 1023) / 1024;
    scan1_kernel<<<nb, 256, 0, stream>>>(cnt, offs, bsums, N);
    scan2_kernel<<<1, 256, 0, stream>>>(bsums, nb);
    scan3_kernel<<<nb, 256, 0, stream>>>(offs, bsums, cursor, N, E);
    fill_csr_kernel<<<(E + 255) / 256, 256, 0, stream>>>(eidx, sflag, cursor, csr_src, E);

    for (int ms = 0; ms < N; ms += CH) {
        int mc = (N - ms < CH) ? (N - ms) : CH;
        dim3 g1(4, (mc + 63) / 64);
        gemm_kernel<<<g1, 256, 0, stream>>>(x + (size_t)ms * 256, 256, W1, 256, b1,
                                            h1, 256, mc, 1);
        dim3 g2(1, (mc + 63) / 64);
        gemm_kernel<<<g2, 256, 0, stream>>>(h1, 256, W2, 64, b2,
                                            hA + (size_t)ms * 64, 64, mc, 0);
    }

    int nwb = (N + 3) / 4;  // 4 waves (=4 dest nodes) per 256-thread block
    hop0_kernel<<<nwb, 256, 0, stream>>>(hA, dinv, pw, pb, out, gA, N);
    __hip_bfloat16* gin = gA;
    __hip_bfloat16* gout = gB;
    for (int k = 0; k < 10; ++k) {
        spmm_kernel<<<nwb, 256, 0, stream>>>(offs, csr_src, dinv, gin, gout, out, pw, pb, N);
        __hip_bfloat16* t = gin; gin = gout; gout = t;
    }
}